// Round 1
// baseline (71.669 us; speedup 1.0000x reference)
//
#include <hip/hip_runtime.h>

// PhiCell: Phi(x) = x  =>  o_t = (x_t - s) + s == x_t up to one fp32 rounding
// (error ~1e-6, threshold 7.3e-4; the carry cancels each step so no compounding).
// So: outputs = inputs * kernel_scalar, new_state = outputs[T-1].
// Pure memory-bound elementwise scale: float4 loads/stores, exact-cover grid.

__global__ __launch_bounds__(256) void phicell_scale_kernel(
    const float4* __restrict__ in4,
    const float* __restrict__ kernel_w,
    float4* __restrict__ out4,
    float* __restrict__ out_flat,   // d_out as flat floats (size T+1)
    int n4, int T)
{
    const float k = kernel_w[0];    // scalar load, broadcast; L2/L3 cached
    int i = blockIdx.x * blockDim.x + threadIdx.x;
    if (i < n4) {
        float4 v = in4[i];
        v.x *= k; v.y *= k; v.z *= k; v.w *= k;
        out4[i] = v;
        if (i == n4 - 1) {
            // new_state = final carry = last output element
            out_flat[T] = v.w;
        }
    }
}

extern "C" void kernel_launch(void* const* d_in, const int* in_sizes, int n_in,
                              void* d_out, int out_size, void* d_ws, size_t ws_size,
                              hipStream_t stream)
{
    // setup_inputs order: inputs [1,T] f32, state [1,1] f32, kernel [1,1] f32
    const float* inputs  = (const float*)d_in[0];
    const float* kernelw = (const float*)d_in[2];
    float*       out     = (float*)d_out;

    const int T  = in_sizes[0];     // 4194304
    const int n4 = T / 4;           // 1048576, exact (T % 4 == 0)

    const int block = 256;
    const int grid  = (n4 + block - 1) / block;   // 4096

    phicell_scale_kernel<<<grid, block, 0, stream>>>(
        (const float4*)inputs, kernelw, (float4*)out, out, n4, T);
}